// Round 2
// baseline (330.782 us; speedup 1.0000x reference)
//
#include <hip/hip_runtime.h>

typedef __attribute__((ext_vector_type(8))) short short8;
typedef __attribute__((ext_vector_type(4))) float f32x4;

#define GLD_AS1 const __attribute__((address_space(1))) void*
#define GLD_AS3 __attribute__((address_space(3))) void*

__device__ __forceinline__ unsigned short f2bf(float f) {
  unsigned u = __builtin_bit_cast(unsigned, f);
  u += 0x7fffu + ((u >> 16) & 1u);   // round-to-nearest-even
  return (unsigned short)(u >> 16);
}

// ---------------- fp32 -> bf16 convert (vectorized, grid-stride) ----------------
__global__ void cvt_f32_bf16(const float* __restrict__ in, unsigned short* __restrict__ out, int n4) {
  int i = blockIdx.x * blockDim.x + threadIdx.x;
  const int st = gridDim.x * blockDim.x;
  for (; i < n4; i += st) {
    float4 f = reinterpret_cast<const float4*>(in)[i];
    unsigned long long p = (unsigned long long)f2bf(f.x)
        | ((unsigned long long)f2bf(f.y) << 16)
        | ((unsigned long long)f2bf(f.z) << 32)
        | ((unsigned long long)f2bf(f.w) << 48);
    reinterpret_cast<unsigned long long*>(out)[i] = p;
  }
}

// ---------------- fused QKV projection ----------------
// Y[16384,1536] = xb[16384,512] @ Wcat[1536,512]^T ; n in [0,512)->Q, [512,1024)->K,
// [1024,1536)->V stored TRANSPOSED as Vt[b][d][s] for the attention PV B-operand.
// 128x128 tile, 4 waves (each 64x64 = 4x4 MFMA frags), BK=64, global_load_lds(16B)
// with XOR-swizzled global source (LDS dest stays linear; read applies same XOR).
__global__ __launch_bounds__(256) void qkv_gemm(
    const unsigned short* __restrict__ xb, const unsigned short* __restrict__ wcat,
    unsigned short* __restrict__ qb, unsigned short* __restrict__ kb,
    unsigned short* __restrict__ vtb) {
  __shared__ unsigned short As[128 * 64];
  __shared__ unsigned short Bs[128 * 64];
  const int tid = threadIdx.x, lane = tid & 63, w = tid >> 6;
  const int m0 = blockIdx.x * 128, n0 = blockIdx.y * 128;
  const int wr = w >> 1, wc = w & 1;

  f32x4 acc[4][4];
  const f32x4 z4 = {0.f, 0.f, 0.f, 0.f};
  #pragma unroll
  for (int a = 0; a < 4; ++a)
    #pragma unroll
    for (int c = 0; c < 4; ++c) acc[a][c] = z4;

  for (int it = 0; it < 8; ++it) {
    const int k0 = it * 64;
    #pragma unroll
    for (int c = 0; c < 4; ++c) {
      const int rbase = 32 * w + 8 * c;            // wave-uniform LDS row base
      const int r = rbase + (lane >> 3);           // per-lane tile row
      const int c16 = (lane & 7) ^ (r & 7);        // swizzled global 16B-chunk
      const unsigned short* ga = xb + (size_t)(m0 + r) * 512 + k0 + c16 * 8;
      const unsigned short* gb = wcat + (size_t)(n0 + r) * 512 + k0 + c16 * 8;
      __builtin_amdgcn_global_load_lds((GLD_AS1)ga, (GLD_AS3)&As[rbase * 64], 16, 0, 0);
      __builtin_amdgcn_global_load_lds((GLD_AS1)gb, (GLD_AS3)&Bs[rbase * 64], 16, 0, 0);
    }
    __syncthreads();
    #pragma unroll
    for (int ks = 0; ks < 2; ++ks) {
      const int ck = ks * 4 + (lane >> 4);
      short8 av[4], bv[4];
      #pragma unroll
      for (int fr = 0; fr < 4; ++fr) {
        const int rl = 64 * wr + 16 * fr + (lane & 15);
        av[fr] = *reinterpret_cast<const short8*>(&As[rl * 64 + ((ck ^ (rl & 7)) << 3)]);
      }
      #pragma unroll
      for (int fc = 0; fc < 4; ++fc) {
        const int rl = 64 * wc + 16 * fc + (lane & 15);
        bv[fc] = *reinterpret_cast<const short8*>(&Bs[rl * 64 + ((ck ^ (rl & 7)) << 3)]);
      }
      #pragma unroll
      for (int fr = 0; fr < 4; ++fr)
        #pragma unroll
        for (int fc = 0; fc < 4; ++fc)
          acc[fr][fc] = __builtin_amdgcn_mfma_f32_16x16x32_bf16(av[fr], bv[fc], acc[fr][fc], 0, 0, 0);
    }
    __syncthreads();
  }

  const int which = n0 >> 9;  // uniform per block (128 | 512)
  #pragma unroll
  for (int fr = 0; fr < 4; ++fr) {
    #pragma unroll
    for (int fc = 0; fc < 4; ++fc) {
      const int n = n0 + 64 * wc + 16 * fc + (lane & 15);
      const int nl = n & 511;
      #pragma unroll
      for (int j = 0; j < 4; ++j) {
        const int m = m0 + 64 * wr + 16 * fr + (lane >> 4) * 4 + j;
        const unsigned short v = f2bf(acc[fr][fc][j]);
        if (which == 0)      qb[(size_t)m * 512 + nl] = v;
        else if (which == 1) kb[(size_t)m * 512 + nl] = v;
        else                 vtb[((size_t)((m >> 12) * 512 + nl)) * 4096 + (m & 4095)] = v;
      }
    }
  }
}

// ---------------- causal flash attention ----------------
// QBLK=64, KVBLK=64, 8 waves. grid = (S/64=64, B=4) -> 256 blocks, 1/CU.
// Per wave: S-phase computes S rows 16*(w&3), cols 32*(w>>2) (2 frags, K=512);
// softmax owns rows 8w..8w+7 (8 lanes/row); PV owns d-chunk 64w..64w+63.
// Q hoisted in registers; K tile in LDS (XOR-swizzled via pre-swizzled global src);
// V read from transposed Vt. 2 barriers/tile; next-K stage overlaps softmax.
// OUTPUT IS FP32 (reference returns float32).
__global__ __launch_bounds__(512) void attn_fwd(
    const unsigned short* __restrict__ qg, const unsigned short* __restrict__ kg,
    const unsigned short* __restrict__ vtg, float* __restrict__ outg) {
  __shared__ unsigned short Ks[64 * 512];     // 64KB
  __shared__ float S_lds[64][66];             // stride 66 -> 2-way max on writes
  __shared__ unsigned short P_lds[64][72];    // stride 72 (144B) -> 2-way on b128 reads
  __shared__ float row_f[64];                 // per-tile rescale r; 1/l at the end

  const int tid = threadIdx.x, lane = tid & 63, w = tid >> 6;
  const int qt = blockIdx.x, b = blockIdx.y;
  const int q0 = qt * 64;
  const unsigned short* Qb  = qg  + (size_t)b * 4096 * 512;
  const unsigned short* Kb  = kg  + (size_t)b * 4096 * 512;
  const unsigned short* Vtb = vtg + (size_t)b * 512 * 4096;
  float* outb = outg + (size_t)b * 4096 * 512;

  const int wr = w & 3, wc = w >> 2;
  const int dw = w * 64;
  const int srow = 8 * w + (lane >> 3);
  const float scale = 0.044194173824159216f;  // 1/sqrt(512)

  // Q hoist: 16 k-steps x short8 = 64 VGPRs, constant over all KV tiles
  short8 qreg[16];
  {
    const unsigned short* qrow = Qb + (size_t)(q0 + 16 * wr + (lane & 15)) * 512 + (lane >> 4) * 8;
    #pragma unroll
    for (int ks = 0; ks < 16; ++ks)
      qreg[ks] = *reinterpret_cast<const short8*>(qrow + ks * 32);
  }

  const f32x4 z4 = {0.f, 0.f, 0.f, 0.f};
  f32x4 oacc[4][4];
  #pragma unroll
  for (int fr = 0; fr < 4; ++fr)
    #pragma unroll
    for (int fc = 0; fc < 4; ++fc) oacc[fr][fc] = z4;

  float m_run = -1e30f, l_run = 0.f;

  // prologue: stage K tile 0 (wave w stages rows w, 8+w, ..., 56+w; 1KB per call)
  #pragma unroll
  for (int r8 = 0; r8 < 8; ++r8) {
    const int r = r8 * 8 + w;
    const unsigned short* g = Kb + (size_t)r * 512 + (lane ^ (r & 7)) * 8;
    __builtin_amdgcn_global_load_lds((GLD_AS1)g, (GLD_AS3)&Ks[r * 512], 16, 0, 0);
  }
  __syncthreads();

  for (int kt = 0; kt <= qt; ++kt) {
    const int kv0 = kt * 64;

    // ---- Phase A: S = Q K^T (from Ks LDS + Q regs) ----
    f32x4 sacc[2] = {z4, z4};
    #pragma unroll
    for (int ks = 0; ks < 16; ++ks) {
      const int ck = ks * 4 + (lane >> 4);
      #pragma unroll
      for (int fc = 0; fc < 2; ++fc) {
        const int rl = 32 * wc + 16 * fc + (lane & 15);
        const short8 bv = *reinterpret_cast<const short8*>(&Ks[rl * 512 + ((ck ^ (rl & 7)) << 3)]);
        sacc[fc] = __builtin_amdgcn_mfma_f32_16x16x32_bf16(qreg[ks], bv, sacc[fc], 0, 0, 0);
      }
    }
    #pragma unroll
    for (int fc = 0; fc < 2; ++fc)
      #pragma unroll
      for (int j = 0; j < 4; ++j)
        S_lds[16 * wr + (lane >> 4) * 4 + j][32 * wc + 16 * fc + (lane & 15)] = sacc[fc][j];
    __syncthreads();

    // ---- Phase B: stage next K tile (overlaps softmax) + online softmax ----
    if (kt < qt) {
      const int kv0n = kv0 + 64;
      #pragma unroll
      for (int r8 = 0; r8 < 8; ++r8) {
        const int r = r8 * 8 + w;
        const unsigned short* g = Kb + (size_t)(kv0n + r) * 512 + (lane ^ (r & 7)) * 8;
        __builtin_amdgcn_global_load_lds((GLD_AS1)g, (GLD_AS3)&Ks[r * 512], 16, 0, 0);
      }
    }
    {
      const int c0 = (lane & 7) * 8;
      float v[8];
      #pragma unroll
      for (int i = 0; i < 8; ++i) {
        float s = S_lds[srow][c0 + i] * scale;
        if (kt == qt && (c0 + i) > srow) s = -1e30f;  // causal mask (diagonal tile only)
        v[i] = s;
      }
      float pmax = v[0];
      #pragma unroll
      for (int i = 1; i < 8; ++i) pmax = fmaxf(pmax, v[i]);
      pmax = fmaxf(pmax, __shfl_xor(pmax, 1));
      pmax = fmaxf(pmax, __shfl_xor(pmax, 2));
      pmax = fmaxf(pmax, __shfl_xor(pmax, 4));
      const float m_new = fmaxf(m_run, pmax);
      const float r = __expf(m_run - m_new);
      float psum = 0.f;
      short8 pk;
      #pragma unroll
      for (int i = 0; i < 8; ++i) {
        const float p = __expf(v[i] - m_new);
        psum += p;
        pk[i] = (short)f2bf(p);
      }
      psum += __shfl_xor(psum, 1);
      psum += __shfl_xor(psum, 2);
      psum += __shfl_xor(psum, 4);
      l_run = l_run * r + psum;
      m_run = m_new;
      if ((lane & 7) == 0) row_f[srow] = r;
      *reinterpret_cast<short8*>(&P_lds[srow][c0]) = pk;
    }
    __syncthreads();

    // ---- Phase C: O = O*r + P @ V ----
    #pragma unroll
    for (int fr = 0; fr < 4; ++fr)
      #pragma unroll
      for (int j = 0; j < 4; ++j) {
        const float f = row_f[16 * fr + (lane >> 4) * 4 + j];
        #pragma unroll
        for (int fc = 0; fc < 4; ++fc) oacc[fr][fc][j] *= f;
      }
    #pragma unroll
    for (int ks = 0; ks < 2; ++ks) {
      short8 av[4], bv[4];
      #pragma unroll
      for (int fc = 0; fc < 4; ++fc)
        bv[fc] = *reinterpret_cast<const short8*>(
            Vtb + (size_t)(dw + 16 * fc + (lane & 15)) * 4096 + kv0 + ks * 32 + (lane >> 4) * 8);
      #pragma unroll
      for (int fr = 0; fr < 4; ++fr)
        av[fr] = *reinterpret_cast<const short8*>(&P_lds[16 * fr + (lane & 15)][ks * 32 + (lane >> 4) * 8]);
      #pragma unroll
      for (int fr = 0; fr < 4; ++fr)
        #pragma unroll
        for (int fc = 0; fc < 4; ++fc)
          oacc[fr][fc] = __builtin_amdgcn_mfma_f32_16x16x32_bf16(av[fr], bv[fc], oacc[fr][fc], 0, 0, 0);
    }
    // no barrier needed: next Phase A touches only S_lds/Ks (disjoint from C's reads)
  }

  __syncthreads();
  if ((lane & 7) == 0) row_f[srow] = 1.0f / l_run;
  __syncthreads();
  #pragma unroll
  for (int fr = 0; fr < 4; ++fr)
    #pragma unroll
    for (int j = 0; j < 4; ++j) {
      const int row = 16 * fr + (lane >> 4) * 4 + j;
      const float linv = row_f[row];
      #pragma unroll
      for (int fc = 0; fc < 4; ++fc)
        outb[(size_t)(q0 + row) * 512 + dw + 16 * fc + (lane & 15)] = oacc[fr][fc][j] * linv;
    }
}

extern "C" void kernel_launch(void* const* d_in, const int* in_sizes, int n_in,
                              void* d_out, int out_size, void* d_ws, size_t ws_size,
                              hipStream_t stream) {
  const float* x  = (const float*)d_in[0];
  const float* wq = (const float*)d_in[1];
  const float* wk = (const float*)d_in[2];
  const float* wv = (const float*)d_in[3];

  // workspace layout (needs ~68MB):
  // [0,16MB)   x as bf16            [16384][512]
  // [16,20MB)  Wcat bf16            [1536][512]  (Wq|Wk|Wv rows)
  // [20,36MB)  Q bf16               [b][s][d]
  // [36,52MB)  K bf16               [b][s][d]
  // [52,68MB)  V^T bf16             [b][d][s]
  char* ws = (char*)d_ws;
  unsigned short* xb   = (unsigned short*)(ws);
  unsigned short* wcat = (unsigned short*)(ws + (16u << 20));
  unsigned short* qb   = (unsigned short*)(ws + (20u << 20));
  unsigned short* kb   = (unsigned short*)(ws + (36u << 20));
  unsigned short* vtb  = (unsigned short*)(ws + (52u << 20));

  cvt_f32_bf16<<<2048, 256, 0, stream>>>(x, xb, (4 * 4096 * 512) / 4);
  cvt_f32_bf16<<<256, 256, 0, stream>>>(wq, wcat, (512 * 512) / 4);
  cvt_f32_bf16<<<256, 256, 0, stream>>>(wk, wcat + 512 * 512, (512 * 512) / 4);
  cvt_f32_bf16<<<256, 256, 0, stream>>>(wv, wcat + 2 * 512 * 512, (512 * 512) / 4);

  qkv_gemm<<<dim3(128, 12), 256, 0, stream>>>(xb, wcat, qb, kb, vtb);

  attn_fwd<<<dim3(64, 4), 512, 0, stream>>>(qb, kb, vtb, (float*)d_out);
}

// Round 3
// 225.206 us; speedup vs baseline: 1.4688x; 1.4688x over previous
//
#include <hip/hip_runtime.h>

typedef __attribute__((ext_vector_type(8))) short short8;
typedef __attribute__((ext_vector_type(4))) float f32x4;

#define GLD_AS1 const __attribute__((address_space(1))) void*
#define GLD_AS3 __attribute__((address_space(3))) void*

__device__ __forceinline__ unsigned short f2bf(float f) {
  unsigned u = __builtin_bit_cast(unsigned, f);
  u += 0x7fffu + ((u >> 16) & 1u);   // round-to-nearest-even
  return (unsigned short)(u >> 16);
}
__device__ __forceinline__ float bf2f(unsigned short h) {
  return __builtin_bit_cast(float, (unsigned)h << 16);
}

// ---------------- fp32 -> bf16 convert (vectorized, grid-stride) ----------------
__global__ void cvt_f32_bf16(const float* __restrict__ in, unsigned short* __restrict__ out, int n4) {
  int i = blockIdx.x * blockDim.x + threadIdx.x;
  const int st = gridDim.x * blockDim.x;
  for (; i < n4; i += st) {
    float4 f = reinterpret_cast<const float4*>(in)[i];
    unsigned long long p = (unsigned long long)f2bf(f.x)
        | ((unsigned long long)f2bf(f.y) << 16)
        | ((unsigned long long)f2bf(f.z) << 32)
        | ((unsigned long long)f2bf(f.w) << 48);
    reinterpret_cast<unsigned long long*>(out)[i] = p;
  }
}

// ---------------- fused QKV projection ----------------
// Y[16384,1536] = xb[16384,512] @ Wcat[1536,512]^T ; n in [0,512)->Q, [512,1024)->K,
// [1024,1536)->V stored TRANSPOSED as Vt[b][d][s].
__global__ __launch_bounds__(256) void qkv_gemm(
    const unsigned short* __restrict__ xb, const unsigned short* __restrict__ wcat,
    unsigned short* __restrict__ qb, unsigned short* __restrict__ kb,
    unsigned short* __restrict__ vtb) {
  __shared__ unsigned short As[128 * 64];
  __shared__ unsigned short Bs[128 * 64];
  const int tid = threadIdx.x, lane = tid & 63, w = tid >> 6;
  const int m0 = blockIdx.x * 128, n0 = blockIdx.y * 128;
  const int wr = w >> 1, wc = w & 1;

  f32x4 acc[4][4];
  const f32x4 z4 = {0.f, 0.f, 0.f, 0.f};
  #pragma unroll
  for (int a = 0; a < 4; ++a)
    #pragma unroll
    for (int c = 0; c < 4; ++c) acc[a][c] = z4;

  for (int it = 0; it < 8; ++it) {
    const int k0 = it * 64;
    #pragma unroll
    for (int c = 0; c < 4; ++c) {
      const int rbase = 32 * w + 8 * c;            // wave-uniform LDS row base
      const int r = rbase + (lane >> 3);           // per-lane tile row
      const int c16 = (lane & 7) ^ (r & 7);        // swizzled global 16B-chunk
      const unsigned short* ga = xb + (size_t)(m0 + r) * 512 + k0 + c16 * 8;
      const unsigned short* gb = wcat + (size_t)(n0 + r) * 512 + k0 + c16 * 8;
      __builtin_amdgcn_global_load_lds((GLD_AS1)ga, (GLD_AS3)&As[rbase * 64], 16, 0, 0);
      __builtin_amdgcn_global_load_lds((GLD_AS1)gb, (GLD_AS3)&Bs[rbase * 64], 16, 0, 0);
    }
    __syncthreads();
    #pragma unroll
    for (int ks = 0; ks < 2; ++ks) {
      const int ck = ks * 4 + (lane >> 4);
      short8 av[4], bv[4];
      #pragma unroll
      for (int fr = 0; fr < 4; ++fr) {
        const int rl = 64 * wr + 16 * fr + (lane & 15);
        av[fr] = *reinterpret_cast<const short8*>(&As[rl * 64 + ((ck ^ (rl & 7)) << 3)]);
      }
      #pragma unroll
      for (int fc = 0; fc < 4; ++fc) {
        const int rl = 64 * wc + 16 * fc + (lane & 15);
        bv[fc] = *reinterpret_cast<const short8*>(&Bs[rl * 64 + ((ck ^ (rl & 7)) << 3)]);
      }
      #pragma unroll
      for (int fr = 0; fr < 4; ++fr)
        #pragma unroll
        for (int fc = 0; fc < 4; ++fc)
          acc[fr][fc] = __builtin_amdgcn_mfma_f32_16x16x32_bf16(av[fr], bv[fc], acc[fr][fc], 0, 0, 0);
    }
    __syncthreads();
  }

  const int which = n0 >> 9;  // uniform per block
  #pragma unroll
  for (int fr = 0; fr < 4; ++fr) {
    #pragma unroll
    for (int fc = 0; fc < 4; ++fc) {
      const int n = n0 + 64 * wc + 16 * fc + (lane & 15);
      const int nl = n & 511;
      #pragma unroll
      for (int j = 0; j < 4; ++j) {
        const int m = m0 + 64 * wr + 16 * fr + (lane >> 4) * 4 + j;
        const unsigned short v = f2bf(acc[fr][fc][j]);
        if (which == 0)      qb[(size_t)m * 512 + nl] = v;
        else if (which == 1) kb[(size_t)m * 512 + nl] = v;
        else                 vtb[((size_t)((m >> 12) * 512 + nl)) * 4096 + (m & 4095)] = v;
      }
    }
  }
}

// ---------------- causal flash attention, split-KV ----------------
// Each (b,qt) handled by TWO blocks: half0 = kt in [0,nkt/2), half1 = [nkt/2,nkt)
// (half1 contains the masked diagonal tile and is never empty).
// Blocks write UNNORMALIZED O' + per-row (m,l); a merge kernel combines.
// 8 waves, QBLK=64, KVBLK=64, double-buffered Ks, V prefetched to registers,
// next-K staged at top of Phase A (drain window = whole Phase A).
// LPT: blockIdx.x ordered so qt=63 blocks dispatch first.
__global__ __launch_bounds__(512) void attn_fwd(
    const unsigned short* __restrict__ qg, const unsigned short* __restrict__ kg,
    const unsigned short* __restrict__ vtg,
    float* __restrict__ out0,            // [B][S][512] fp32 unnormalized (half 0)
    unsigned short* __restrict__ out1,   // [B][S][512] bf16 unnormalized (half 1)
    float* __restrict__ ml) {            // [4][B*S] : m0,l0,m1,l1
  __shared__ unsigned short Ks[2][64 * 512];  // 128KB double buffer
  __shared__ float S_lds[64][66];
  __shared__ unsigned short P_lds[64][72];
  __shared__ float row_f[64];

  const int tid = threadIdx.x, lane = tid & 63, w = tid >> 6;
  const int idx = blockIdx.x;            // 0..511
  const int qt = 63 - (idx >> 3);        // LPT: big qt first
  const int b = (idx >> 1) & 3;
  const int half = idx & 1;
  const int nkt = qt + 1;
  const int kt0 = half ? (nkt >> 1) : 0;
  const int kt1 = half ? nkt : (nkt >> 1);
  const int q0 = qt * 64;

  const unsigned short* Qb  = qg  + (size_t)b * 4096 * 512;
  const unsigned short* Kb  = kg  + (size_t)b * 4096 * 512;
  const unsigned short* Vtb = vtg + (size_t)b * 512 * 4096;

  const int wr = w & 3, wc = w >> 2;
  const int dw = w * 64;
  const int srow = 8 * w + (lane >> 3);
  const float scale = 0.044194173824159216f;  // 1/sqrt(512)

  // Q hoist: 16 k-steps x short8 = 64 VGPRs
  short8 qreg[16];
  {
    const unsigned short* qrow = Qb + (size_t)(q0 + 16 * wr + (lane & 15)) * 512 + (lane >> 4) * 8;
    #pragma unroll
    for (int ks = 0; ks < 16; ++ks)
      qreg[ks] = *reinterpret_cast<const short8*>(qrow + ks * 32);
  }

  const f32x4 z4 = {0.f, 0.f, 0.f, 0.f};
  f32x4 oacc[4][4];
  #pragma unroll
  for (int fr = 0; fr < 4; ++fr)
    #pragma unroll
    for (int fc = 0; fc < 4; ++fc) oacc[fr][fc] = z4;

  float m_run = -1e30f, l_run = 0.f;

  // prologue: stage K tile kt0 into buffer 0
  if (kt0 < kt1) {
    #pragma unroll
    for (int r8 = 0; r8 < 8; ++r8) {
      const int r = r8 * 8 + w;
      const unsigned short* g = Kb + (size_t)(kt0 * 64 + r) * 512 + (lane ^ (r & 7)) * 8;
      __builtin_amdgcn_global_load_lds((GLD_AS1)g, (GLD_AS3)&Ks[0][r * 512], 16, 0, 0);
    }
  }
  __syncthreads();

  int cur = 0;
  for (int kt = kt0; kt < kt1; ++kt, cur ^= 1) {
    const int kv0 = kt * 64;

    // V tile -> registers (consumed in Phase C; drained by the A->B barrier)
    short8 vreg[2][4];
    #pragma unroll
    for (int ks = 0; ks < 2; ++ks)
      #pragma unroll
      for (int fc = 0; fc < 4; ++fc)
        vreg[ks][fc] = *reinterpret_cast<const short8*>(
            Vtb + (size_t)(dw + 16 * fc + (lane & 15)) * 4096 + kv0 + ks * 32 + (lane >> 4) * 8);

    // stage next K tile into the idle buffer (drain window = whole Phase A)
    if (kt + 1 < kt1) {
      #pragma unroll
      for (int r8 = 0; r8 < 8; ++r8) {
        const int r = r8 * 8 + w;
        const unsigned short* g = Kb + (size_t)((kt + 1) * 64 + r) * 512 + (lane ^ (r & 7)) * 8;
        __builtin_amdgcn_global_load_lds((GLD_AS1)g, (GLD_AS3)&Ks[cur ^ 1][r * 512], 16, 0, 0);
      }
    }

    // ---- Phase A: S = Q K^T from Ks[cur] ----
    f32x4 sacc[2] = {z4, z4};
    #pragma unroll
    for (int ks = 0; ks < 16; ++ks) {
      const int ck = ks * 4 + (lane >> 4);
      #pragma unroll
      for (int fc = 0; fc < 2; ++fc) {
        const int rl = 32 * wc + 16 * fc + (lane & 15);
        const short8 bv = *reinterpret_cast<const short8*>(&Ks[cur][rl * 512 + ((ck ^ (rl & 7)) << 3)]);
        sacc[fc] = __builtin_amdgcn_mfma_f32_16x16x32_bf16(qreg[ks], bv, sacc[fc], 0, 0, 0);
      }
    }
    #pragma unroll
    for (int fc = 0; fc < 2; ++fc)
      #pragma unroll
      for (int j = 0; j < 4; ++j)
        S_lds[16 * wr + (lane >> 4) * 4 + j][32 * wc + 16 * fc + (lane & 15)] = sacc[fc][j];
    __syncthreads();

    // ---- Phase B: online softmax (rows 8w..8w+7, 8 lanes/row) ----
    {
      const int c0 = (lane & 7) * 8;
      float v[8];
      #pragma unroll
      for (int i = 0; i < 8; ++i) {
        float s = S_lds[srow][c0 + i] * scale;
        if (kt == qt && (c0 + i) > srow) s = -1e30f;  // causal mask (diagonal tile)
        v[i] = s;
      }
      float pmax = v[0];
      #pragma unroll
      for (int i = 1; i < 8; ++i) pmax = fmaxf(pmax, v[i]);
      pmax = fmaxf(pmax, __shfl_xor(pmax, 1));
      pmax = fmaxf(pmax, __shfl_xor(pmax, 2));
      pmax = fmaxf(pmax, __shfl_xor(pmax, 4));
      const float m_new = fmaxf(m_run, pmax);
      const float r = __expf(m_run - m_new);
      float psum = 0.f;
      short8 pk;
      #pragma unroll
      for (int i = 0; i < 8; ++i) {
        const float p = __expf(v[i] - m_new);
        psum += p;
        pk[i] = (short)f2bf(p);
      }
      psum += __shfl_xor(psum, 1);
      psum += __shfl_xor(psum, 2);
      psum += __shfl_xor(psum, 4);
      l_run = l_run * r + psum;
      m_run = m_new;
      if ((lane & 7) == 0) row_f[srow] = r;
      *reinterpret_cast<short8*>(&P_lds[srow][c0]) = pk;
    }
    __syncthreads();

    // ---- Phase C: O = O*r + P @ V (V already in registers) ----
    #pragma unroll
    for (int fr = 0; fr < 4; ++fr)
      #pragma unroll
      for (int j = 0; j < 4; ++j) {
        const float f = row_f[16 * fr + (lane >> 4) * 4 + j];
        #pragma unroll
        for (int fc = 0; fc < 4; ++fc) oacc[fr][fc][j] *= f;
      }
    #pragma unroll
    for (int ks = 0; ks < 2; ++ks) {
      short8 av[4];
      #pragma unroll
      for (int fr = 0; fr < 4; ++fr)
        av[fr] = *reinterpret_cast<const short8*>(&P_lds[16 * fr + (lane & 15)][ks * 32 + (lane >> 4) * 8]);
      #pragma unroll
      for (int fr = 0; fr < 4; ++fr)
        #pragma unroll
        for (int fc = 0; fc < 4; ++fc)
          oacc[fr][fc] = __builtin_amdgcn_mfma_f32_16x16x32_bf16(av[fr], vreg[ks][fc], oacc[fr][fc], 0, 0, 0);
    }
    // no barrier: next iter's writes (Ks[cur^1], S_lds) are read-disjoint from C
  }

  // ---- epilogue: write UNNORMALIZED O' and per-row (m,l) ----
  if ((lane & 7) == 0) {
    const int rg = b * 4096 + q0 + srow;
    ml[(half * 2) * 16384 + rg]     = m_run;
    ml[(half * 2 + 1) * 16384 + rg] = l_run;
  }
  if (half == 0) {
    float* ob = out0 + (size_t)b * 4096 * 512;
    #pragma unroll
    for (int fr = 0; fr < 4; ++fr)
      #pragma unroll
      for (int j = 0; j < 4; ++j) {
        const int row = 16 * fr + (lane >> 4) * 4 + j;
        #pragma unroll
        for (int fc = 0; fc < 4; ++fc)
          ob[(size_t)(q0 + row) * 512 + dw + 16 * fc + (lane & 15)] = oacc[fr][fc][j];
      }
  } else {
    unsigned short* ob = out1 + (size_t)b * 4096 * 512;
    #pragma unroll
    for (int fr = 0; fr < 4; ++fr)
      #pragma unroll
      for (int j = 0; j < 4; ++j) {
        const int row = 16 * fr + (lane >> 4) * 4 + j;
        #pragma unroll
        for (int fc = 0; fc < 4; ++fc)
          ob[(size_t)(q0 + row) * 512 + dw + 16 * fc + (lane & 15)] = f2bf(oacc[fr][fc][j]);
      }
  }
}

// ---------------- merge the two KV-halves ----------------
__global__ void attn_merge(float* __restrict__ out, const unsigned short* __restrict__ o1,
                           const float* __restrict__ ml) {
  const int total = 16384 * 128;  // float4 granules
  int i = blockIdx.x * blockDim.x + threadIdx.x;
  const int st = gridDim.x * blockDim.x;
  for (; i < total; i += st) {
    const int r = i >> 7;
    const float m0 = ml[r], l0 = ml[16384 + r];
    const float m1 = ml[2 * 16384 + r], l1 = ml[3 * 16384 + r];
    const float m = fmaxf(m0, m1);
    const float a0 = __expf(m0 - m), a1 = __expf(m1 - m);
    const float inv = 1.0f / (a0 * l0 + a1 * l1);  // l1 >= 1 always
    const float s0 = a0 * inv, s1 = a1 * inv;
    float4 v0 = reinterpret_cast<const float4*>(out)[i];
    ushort4 v1 = reinterpret_cast<const ushort4*>(o1)[i];
    float4 o;
    o.x = v0.x * s0 + bf2f(v1.x) * s1;
    o.y = v0.y * s0 + bf2f(v1.y) * s1;
    o.z = v0.z * s0 + bf2f(v1.z) * s1;
    o.w = v0.w * s0 + bf2f(v1.w) * s1;
    reinterpret_cast<float4*>(out)[i] = o;
  }
}

extern "C" void kernel_launch(void* const* d_in, const int* in_sizes, int n_in,
                              void* d_out, int out_size, void* d_ws, size_t ws_size,
                              hipStream_t stream) {
  const float* x  = (const float*)d_in[0];
  const float* wq = (const float*)d_in[1];
  const float* wk = (const float*)d_in[2];
  const float* wv = (const float*)d_in[3];

  // workspace layout (~68MB):
  // [0,16MB)    x bf16 [16384][512]  -- later REUSED as half1 partial O' (bf16)
  // [16,17.5MB) Wcat bf16 [1536][512]
  // [18,19MB)   ml float [4][16384]
  // [20,36MB)   Q bf16   [36,52MB) K bf16   [52,68MB) V^T bf16 [b][d][s]
  char* ws = (char*)d_ws;
  unsigned short* xb   = (unsigned short*)(ws);
  unsigned short* wcat = (unsigned short*)(ws + (16u << 20));
  float*          mlp  = (float*)(ws + (18u << 20));
  unsigned short* qb   = (unsigned short*)(ws + (20u << 20));
  unsigned short* kb   = (unsigned short*)(ws + (36u << 20));
  unsigned short* vtb  = (unsigned short*)(ws + (52u << 20));

  cvt_f32_bf16<<<2048, 256, 0, stream>>>(x, xb, (4 * 4096 * 512) / 4);
  cvt_f32_bf16<<<256, 256, 0, stream>>>(wq, wcat, (512 * 512) / 4);
  cvt_f32_bf16<<<256, 256, 0, stream>>>(wk, wcat + 512 * 512, (512 * 512) / 4);
  cvt_f32_bf16<<<256, 256, 0, stream>>>(wv, wcat + 2 * 512 * 512, (512 * 512) / 4);

  qkv_gemm<<<dim3(128, 12), 256, 0, stream>>>(xb, wcat, qb, kb, vtb);

  // split-KV attention: 512 blocks (qt-descending LPT), partials + merge.
  // out1 reuses the xb region (x no longer needed after qkv_gemm).
  attn_fwd<<<512, 512, 0, stream>>>(qb, kb, vtb, (float*)d_out, xb, mlp);
  attn_merge<<<2048, 256, 0, stream>>>((float*)d_out, xb, mlp);
}